// Round 15
// baseline (203.973 us; speedup 1.0000x reference)
//
#include <hip/hip_runtime.h>
#include <hip/hip_bf16.h>
#include <stdint.h>

#define DIMM  1024
#define NHEAD 16
#define DHEAD 64
#define BB    2
#define SQL   2048
#define SKL   4096
#define KVW   2048   // kv row width = 2*INNER
#define NT    (SKL / 64)

typedef __attribute__((ext_vector_type(8))) short short8;
typedef __attribute__((ext_vector_type(4))) float f32x4;
typedef __attribute__((ext_vector_type(16))) float f32x16;
typedef __attribute__((ext_vector_type(4))) unsigned short us4;

typedef const __attribute__((address_space(1))) uint32_t gu32_t;
typedef __attribute__((address_space(3))) uint32_t lu32_t;

#define GLDS16(gp, lp) __builtin_amdgcn_global_load_lds((gu32_t*)(gp), (lu32_t*)(lp), 16, 0, 0)

static __device__ __forceinline__ unsigned short f2bf(float f) {
  union { float f; uint32_t u; } v; v.f = f;
  uint32_t r = v.u + 0x7fffu + ((v.u >> 16) & 1u);
  return (unsigned short)(r >> 16);
}

// ---------- merged prep: weight transposes + LayerNorm + ctx cast, ONE launch ----------
__global__ __launch_bounds__(256) void k_prep(const float* __restrict__ wq,
                                              const float* __restrict__ wkv,
                                              const float* __restrict__ wot,
                                              const float* __restrict__ x,
                                              const float* __restrict__ gamma,
                                              const float* __restrict__ beta,
                                              const float* __restrict__ ctx,
                                              unsigned short* __restrict__ WQT,
                                              unsigned short* __restrict__ WKVT,
                                              unsigned short* __restrict__ WOT,
                                              unsigned short* __restrict__ XN,
                                              unsigned short* __restrict__ CTXB) {
  const int bid = blockIdx.x;
  const int tid = threadIdx.x;

  if (bid < 4096) {
    __shared__ float tile[32][33];
    const float* in; unsigned short* out; int N, bx, by;
    if (bid < 1024)      {                    in = wq;  out = WQT;  N = 1024; bx = bid & 31; by = bid >> 5; }
    else if (bid < 3072) { int l = bid - 1024; in = wkv; out = WKVT; N = 2048; bx = l & 63; by = l >> 6; }
    else                 { int l = bid - 3072; in = wot; out = WOT;  N = 1024; bx = l & 31; by = l >> 5; }
    const int K = 1024;
    const int n0 = bx * 32, k0 = by * 32;
    const int tx = tid & 31, ty = tid >> 5;
    #pragma unroll
    for (int i = 0; i < 4; i++)
      tile[ty + i * 8][tx] = in[(size_t)(k0 + ty + i * 8) * N + n0 + tx];
    __syncthreads();
    #pragma unroll
    for (int i = 0; i < 4; i++)
      out[(size_t)(n0 + ty + i * 8) * K + k0 + tx] = f2bf(tile[tx][ty + i * 8]);
  } else if (bid < 8192) {
    const int row = bid - 4096;
    const float* xr = x + (size_t)row * DIMM;
    float4 v = *(const float4*)(xr + tid * 4);
    float s = v.x + v.y + v.z + v.w;
    float ss = v.x * v.x + v.y * v.y + v.z * v.z + v.w * v.w;
    #pragma unroll
    for (int m = 1; m < 64; m <<= 1) {
      s += __shfl_xor(s, m);
      ss += __shfl_xor(ss, m);
    }
    __shared__ float red[8];
    const int wid = tid >> 6, lane = tid & 63;
    if (lane == 0) { red[wid] = s; red[4 + wid] = ss; }
    __syncthreads();
    s = red[0] + red[1] + red[2] + red[3];
    ss = red[4] + red[5] + red[6] + red[7];
    float mu = s * (1.0f / DIMM);
    float var = ss * (1.0f / DIMM) - mu * mu;
    float rstd = rsqrtf(var + 1e-5f);
    float4 g = *(const float4*)(gamma + tid * 4);
    float4 bt = *(const float4*)(beta + tid * 4);
    us4 o;
    o.x = f2bf((v.x - mu) * rstd * g.x + bt.x);
    o.y = f2bf((v.y - mu) * rstd * g.y + bt.y);
    o.z = f2bf((v.z - mu) * rstd * g.z + bt.z);
    o.w = f2bf((v.w - mu) * rstd * g.w + bt.w);
    *(us4*)(XN + (size_t)row * DIMM + tid * 4) = o;
  } else {
    size_t i = ((size_t)(bid - 8192) * 256 + tid) * 8;
    float4 v0 = *(const float4*)(ctx + i);
    float4 v1 = *(const float4*)(ctx + i + 4);
    union { us4 h[2]; short8 s; } o;
    o.h[0].x = f2bf(v0.x); o.h[0].y = f2bf(v0.y); o.h[0].z = f2bf(v0.z); o.h[0].w = f2bf(v0.w);
    o.h[1].x = f2bf(v1.x); o.h[1].y = f2bf(v1.y); o.h[1].z = f2bf(v1.z); o.h[1].w = f2bf(v1.w);
    *(short8*)(CTXB + i) = o.s;
  }
}

// ---------- fused projection GEMM: Q = XN@WQT^T and KV = CTXB@WKVT^T ----------
__global__ __launch_bounds__(256) void k_proj(const unsigned short* __restrict__ CTXB,
                                              const unsigned short* __restrict__ XN,
                                              const unsigned short* __restrict__ WKVT,
                                              const unsigned short* __restrict__ WQT,
                                              unsigned short* __restrict__ KVB,
                                              unsigned short* __restrict__ QB) {
  __shared__ unsigned short lA[2][128 * 32];
  __shared__ unsigned short lB[2][128 * 32];
  const int tid = threadIdx.x;
  const int wid = tid >> 6, lane = tid & 63;
  const int kg = lane >> 4, lr = lane & 15;
  const int wr = wid >> 1, wc = wid & 1;
  const int K = 1024, nt = 32;

  const int bid = blockIdx.x;
  const int xcd = bid & 7;
  const int idx = bid >> 3;
  const bool isQ = (idx >= 128);
  int im, in_, N;
  const unsigned short* Ap;
  const unsigned short* Bw;
  unsigned short* Cout;
  if (isQ) { int q = idx - 128; im = xcd * 4 + (q & 3);   in_ = q >> 2;   Bw = WQT;  Cout = QB;  N = 1024; Ap = XN; }
  else     {                    im = xcd * 8 + (idx & 7); in_ = idx >> 3; Bw = WKVT; Cout = KVB; N = 2048; Ap = CTXB; }
  const size_t baseB = (size_t)in_ * 128 * K;
  const unsigned short* Abf = Ap + (size_t)im * 128 * K;

  int ed[2], grow[2], gcol[2];
  #pragma unroll
  for (int j = 0; j < 2; j++) {
    int e = wid * 1024 + j * 512 + lane * 8;
    ed[j] = e;
    int row = e >> 5;
    grow[j] = row;
    gcol[j] = (((e >> 3) & 3) ^ ((row >> 1) & 3)) << 3;
  }

  f32x4 acc[4][4];
  #pragma unroll
  for (int m = 0; m < 4; m++)
    #pragma unroll
    for (int n = 0; n < 4; n++) {
      f32x4 z = {0.0f, 0.0f, 0.0f, 0.0f};
      acc[m][n] = z;
    }

  auto STAGE = [&](int bufi, int t) {
    int k0 = t << 5;
    #pragma unroll
    for (int j = 0; j < 2; j++) {
      GLDS16(Abf + (size_t)grow[j] * K + k0 + gcol[j], &lA[bufi][ed[j]]);
      GLDS16(Bw + baseB + (size_t)grow[j] * K + k0 + gcol[j], &lB[bufi][ed[j]]);
    }
  };
  auto COMPUTE = [&](int bufi) {
    short8 a[4], b[4];
    #pragma unroll
    for (int m = 0; m < 4; m++) {
      int row = wr * 64 + m * 16 + lr;
      a[m] = *(const short8*)&lA[bufi][row * 32 + ((kg ^ ((row >> 1) & 3)) << 3)];
    }
    #pragma unroll
    for (int n = 0; n < 4; n++) {
      int row = wc * 64 + n * 16 + lr;
      b[n] = *(const short8*)&lB[bufi][row * 32 + ((kg ^ ((row >> 1) & 3)) << 3)];
    }
    #pragma unroll
    for (int m = 0; m < 4; m++)
      #pragma unroll
      for (int n = 0; n < 4; n++)
        acc[m][n] = __builtin_amdgcn_mfma_f32_16x16x32_bf16(a[m], b[n], acc[m][n], 0, 0, 0);
  };

  STAGE(0, 0);
  __syncthreads();
  int buf = 0;
  for (int t = 0; t < nt; t++) {
    if (t + 1 < nt) STAGE(buf ^ 1, t + 1);
    COMPUTE(buf);
    __syncthreads();
    buf ^= 1;
  }

  const int r0 = im * 128 + wr * 64;
  const int c0 = in_ * 128 + wc * 64;
  #pragma unroll
  for (int m = 0; m < 4; m++)
    #pragma unroll
    for (int n = 0; n < 4; n++)
      #pragma unroll
      for (int j = 0; j < 4; j++)
        Cout[(size_t)(r0 + m * 16 + kg * 4 + j) * N + c0 + n * 16 + lr] = f2bf(acc[m][n][j]);
}

// ---------- output GEMM: out = (OB@WOT^T + bias) * tanh(gate), f32 out ----------
__global__ __launch_bounds__(256) void k_out(const unsigned short* __restrict__ A,
                                             const unsigned short* __restrict__ BT,
                                             float* __restrict__ C,
                                             const float* __restrict__ bias,
                                             const float* __restrict__ gate) {
  __shared__ unsigned short lA[2][64 * 32];
  __shared__ unsigned short lB[2][128 * 32];
  const int tid = threadIdx.x;
  const int wid = tid >> 6, lane = tid & 63;
  const int kg = lane >> 4, lr = lane & 15;
  const int wr = wid >> 1, wc = wid & 1;
  const int K = 1024, nt = 32, N = 1024;

  const int bid = blockIdx.x;
  const int xcd = bid & 7;
  const int idx = bid >> 3;
  const int im = xcd * 8 + (idx & 7);
  const int in_ = idx >> 3;
  const size_t baseA = (size_t)im * 64 * K;
  const size_t baseB = (size_t)in_ * 128 * K;

  int eA, arow, acol;
  {
    int e = tid * 8;
    eA = e;
    int row = e >> 5;
    arow = row; acol = (((e >> 3) & 3) ^ ((row >> 1) & 3)) << 3;
  }
  int eB[2], brow[2], bcol[2];
  #pragma unroll
  for (int j = 0; j < 2; j++) {
    int e = tid * 8 + j * 2048;
    eB[j] = e;
    int row = e >> 5;
    brow[j] = row; bcol[j] = (((e >> 3) & 3) ^ ((row >> 1) & 3)) << 3;
  }

  f32x4 acc[2][4];
  #pragma unroll
  for (int m = 0; m < 2; m++)
    #pragma unroll
    for (int n = 0; n < 4; n++) {
      f32x4 z = {0.0f, 0.0f, 0.0f, 0.0f};
      acc[m][n] = z;
    }

  auto STAGE = [&](int bufi, int t) {
    int k0 = t << 5;
    GLDS16(A + baseA + (size_t)arow * K + k0 + acol, &lA[bufi][eA]);
    #pragma unroll
    for (int j = 0; j < 2; j++)
      GLDS16(BT + baseB + (size_t)brow[j] * K + k0 + bcol[j], &lB[bufi][eB[j]]);
  };

  STAGE(0, 0);
  __syncthreads();
  int buf = 0;
  for (int t = 0; t < nt; t++) {
    if (t + 1 < nt) STAGE(buf ^ 1, t + 1);
    short8 a[2], b[4];
    #pragma unroll
    for (int m = 0; m < 2; m++) {
      int row = wr * 32 + m * 16 + lr;
      a[m] = *(const short8*)&lA[buf][row * 32 + ((kg ^ ((row >> 1) & 3)) << 3)];
    }
    #pragma unroll
    for (int n = 0; n < 4; n++) {
      int row = wc * 64 + n * 16 + lr;
      b[n] = *(const short8*)&lB[buf][row * 32 + ((kg ^ ((row >> 1) & 3)) << 3)];
    }
    #pragma unroll
    for (int m = 0; m < 2; m++)
      #pragma unroll
      for (int n = 0; n < 4; n++)
        acc[m][n] = __builtin_amdgcn_mfma_f32_16x16x32_bf16(a[m], b[n], acc[m][n], 0, 0, 0);
    __syncthreads();
    buf ^= 1;
  }

  const int r0 = im * 64 + wr * 32;
  const int c0 = in_ * 128 + wc * 64;
  float gl = tanhf(gate[0]);
  #pragma unroll
  for (int m = 0; m < 2; m++)
    #pragma unroll
    for (int n = 0; n < 4; n++)
      #pragma unroll
      for (int j = 0; j < 4; j++) {
        int col = c0 + n * 16 + lr;
        C[(size_t)(r0 + m * 16 + kg * 4 + j) * N + col] = (acc[m][n][j] + bias[col]) * gl;
      }
}

// ---------- flash attention v14: v9 + rs-via-MFMA ----------
// P row-sums moved from 16 scalar VALU adds to 2 MFMA (paf x ones) on the
// underused matrix pipe. rsacc C-layout is row-aligned with oacc (reg r <->
// q=rho(r)), so the epilogue's hi-half shuffle + broadcast disappear and the
// normalization divides by the same bf16-quantized P that PV consumes.
__global__ __launch_bounds__(256, 4) void k_attn(const unsigned short* __restrict__ Q,
                                                 const unsigned short* __restrict__ KV,
                                                 unsigned short* __restrict__ O) {
  __shared__ unsigned short sK[2][64 * 64];   // [key][d], granule-swizzled via source
  __shared__ unsigned short sV[2][64 * 64];   // subtiled [key/4][d/16][4][16]

  const int tid = threadIdx.x;
  const int wave = tid >> 6, lane = tid & 63;
  const int wq = wave & 1, wk = wave >> 1;
  const int l31 = lane & 31, hi = lane >> 5;

  const int wid_b = blockIdx.x;
  const int work = (wid_b & 7) * 128 + (wid_b >> 3);
  const int qb = work & 31, bh = work >> 5;
  const int b = bh >> 4, h = bh & 15;

  const unsigned short* Qp = Q + (size_t)b * SQL * DIMM + h * DHEAD;
  const unsigned short* Kp = KV + (size_t)b * SKL * KVW + h * DHEAD;
  const unsigned short* Vp = Kp + DIMM;

  const int qr0 = qb * 64 + wq * 32;

  const unsigned short* ksrc[2]; int kdst[2];
  const unsigned short* vsrc[2]; int vdst[2];
  #pragma unroll
  for (int j = 0; j < 2; j++) {
    int e = (tid + j * 256) * 8;
    int row = e >> 6;
    int col = (((e >> 3) & 7) ^ (row & 7)) << 3;
    ksrc[j] = Kp + (size_t)row * KVW + col;
    kdst[j] = e;
    int g = tid + j * 256;
    int key = (g >> 5) * 4 + ((g >> 1) & 3);
    int d0v = ((g >> 3) & 3) * 16 + (g & 1) * 8;
    vsrc[j] = Vp + (size_t)key * KVW + d0v;
    vdst[j] = g * 8;
  }

  auto STAGE = [&](int bufi, int kt) {
    size_t off = (size_t)kt * 64 * KVW;
    #pragma unroll
    for (int j = 0; j < 2; j++) GLDS16(ksrc[j] + off, &sK[bufi][kdst[j]]);
    #pragma unroll
    for (int j = 0; j < 2; j++) GLDS16(vsrc[j] + off, &sV[bufi][vdst[j]]);
  };

  short8 qa[4];
  #pragma unroll
  for (int t = 0; t < 4; t++) {
    short8 v = *(const short8*)(Qp + (size_t)(qr0 + l31) * DIMM + t * 16 + hi * 8);
    #pragma unroll
    for (int j = 0; j < 8; j++) {
      union { float f; uint32_t u; } c;
      c.u = ((uint32_t)(unsigned short)v[j]) << 16;
      v[j] = (short)f2bf(c.f * 0.1803368801111f);  // 0.125 * log2(e)
    }
    qa[t] = v;
  }

  short8 onesv;
  #pragma unroll
  for (int j = 0; j < 8; j++) onesv[j] = (short)0x3F80;  // bf16 1.0

  f32x16 oacc[2], rsacc;
  #pragma unroll
  for (int d2 = 0; d2 < 2; d2++)
    #pragma unroll
    for (int r = 0; r < 16; r++) oacc[d2][r] = 0.0f;
  #pragma unroll
  for (int r = 0; r < 16; r++) rsacc[r] = 0.0f;

  const uint32_t sVb0 = (uint32_t)(size_t)(lu32_t*)&sV[0][0] +
                        (uint32_t)(hi * 1024 + ((lane >> 4) & 1) * 128 + (lane & 15) * 8);

  STAGE(0, 0);
  __syncthreads();

  union u4s8 { uint32_t u[4]; short8 s; };

  int buf = 0;
  for (int kt = 0; kt < NT; kt++) {
    if (kt + 1 < NT) STAGE(buf ^ 1, kt + 1);

    short8 kbf[4];
    {
      int row = wk * 32 + l31;
      #pragma unroll
      for (int t = 0; t < 4; t++) {
        int gl = t * 2 + hi;
        kbf[t] = *(const short8*)&sK[buf][row * 64 + ((gl ^ (row & 7)) << 3)];
      }
    }

    f32x16 sc;
    #pragma unroll
    for (int r = 0; r < 16; r++) sc[r] = 0.0f;
    #pragma unroll
    for (int t = 0; t < 4; t++)
      sc = __builtin_amdgcn_mfma_f32_32x32x16_bf16(kbf[t], qa[t], sc, 0, 0, 0);

    float p[16];
    #pragma unroll
    for (int r = 0; r < 16; r++)
      p[r] = __builtin_amdgcn_exp2f(sc[r]);
    uint32_t w[8];
    #pragma unroll
    for (int i = 0; i < 8; i++)
      asm("v_cvt_pk_bf16_f32 %0, %1, %2" : "=v"(w[i]) : "v"(p[2 * i]), "v"(p[2 * i + 1]));
    asm("v_permlane32_swap_b32 %0, %1" : "+v"(w[0]), "+v"(w[2]));
    asm("v_permlane32_swap_b32 %0, %1" : "+v"(w[1]), "+v"(w[3]));
    asm("v_permlane32_swap_b32 %0, %1" : "+v"(w[4]), "+v"(w[6]));
    asm("v_permlane32_swap_b32 %0, %1" : "+v"(w[5]), "+v"(w[7]));
    u4s8 paf[2];
    paf[0].u[0] = w[0]; paf[0].u[1] = w[1]; paf[0].u[2] = w[2]; paf[0].u[3] = w[3];
    paf[1].u[0] = w[4]; paf[1].u[1] = w[5]; paf[1].u[2] = w[6]; paf[1].u[3] = w[7];

    // rs via MFMA on the matrix pipe (reg-only; overlaps the tr-read latency)
    rsacc = __builtin_amdgcn_mfma_f32_32x32x16_bf16(paf[0].s, onesv, rsacc, 0, 0, 0);
    rsacc = __builtin_amdgcn_mfma_f32_32x32x16_bf16(paf[1].s, onesv, rsacc, 0, 0, 0);

    u4s8 vb[2][2];
    {
      uint32_t tb = sVb0 + (uint32_t)(buf * 8192 + wk * 4096);
      #pragma unroll
      for (int d2 = 0; d2 < 2; d2++)
        #pragma unroll
        for (int ks = 0; ks < 2; ks++) {
          uint2 t0, t1;
          uint32_t a0 = tb + (uint32_t)(ks * 2048 + d2 * 256);
          asm volatile("ds_read_b64_tr_b16 %0, %1" : "=v"(t0) : "v"(a0));
          asm volatile("ds_read_b64_tr_b16 %0, %1" : "=v"(t1) : "v"(a0 + 512u));
          vb[d2][ks].u[0] = t0.x; vb[d2][ks].u[1] = t0.y;
          vb[d2][ks].u[2] = t1.x; vb[d2][ks].u[3] = t1.y;
        }
    }
    asm volatile("s_waitcnt lgkmcnt(0)" ::: "memory");
    __builtin_amdgcn_sched_barrier(0);

    #pragma unroll
    for (int d2 = 0; d2 < 2; d2++)
      #pragma unroll
      for (int ks = 0; ks < 2; ks++)
        oacc[d2] = __builtin_amdgcn_mfma_f32_32x32x16_bf16(paf[ks].s, vb[d2][ks].s, oacc[d2], 0, 0, 0);

    __syncthreads();
    buf ^= 1;
  }

  // ---- cross-wave (wk) reduction, then normalize + store ----
  float* sRed = (float*)&sK[0][0];   // 2(wq) x 2(d2) x 16(r) x 64(lane) = 16KB
  float* sRs  = (float*)&sV[0][0];   // 2(wq) x 16(r) x 64(lane) = 8KB
  if (wk == 1) {
    #pragma unroll
    for (int d2 = 0; d2 < 2; d2++)
      #pragma unroll
      for (int r = 0; r < 16; r++)
        sRed[((wq * 2 + d2) * 16 + r) * 64 + lane] = oacc[d2][r];
    #pragma unroll
    for (int r = 0; r < 16; r++)
      sRs[(wq * 16 + r) * 64 + lane] = rsacc[r];
  }
  __syncthreads();
  if (wk == 0) {
    #pragma unroll
    for (int d2 = 0; d2 < 2; d2++)
      #pragma unroll
      for (int r = 0; r < 16; r++)
        oacc[d2][r] += sRed[((wq * 2 + d2) * 16 + r) * 64 + lane];
    float inv[16];
    #pragma unroll
    for (int r = 0; r < 16; r++)
      inv[r] = 1.0f / (rsacc[r] + sRs[(wq * 16 + r) * 64 + lane]);
    unsigned short* Op = O + (size_t)b * SQL * DIMM + h * DHEAD;
    #pragma unroll
    for (int d2 = 0; d2 < 2; d2++)
      #pragma unroll
      for (int r = 0; r < 16; r++) {
        int rho = (r & 3) + 8 * (r >> 2) + 4 * hi;
        Op[(size_t)(qr0 + rho) * DIMM + d2 * 32 + l31] = f2bf(oacc[d2][r] * inv[r]);
      }
  }
}

extern "C" void kernel_launch(void* const* d_in, const int* in_sizes, int n_in,
                              void* d_out, int out_size, void* d_ws, size_t ws_size,
                              hipStream_t stream) {
  (void)in_sizes; (void)n_in; (void)out_size; (void)ws_size;
  const float* x     = (const float*)d_in[0];
  const float* ctx   = (const float*)d_in[1];
  const float* gamma = (const float*)d_in[2];
  const float* beta  = (const float*)d_in[3];
  const float* w_q   = (const float*)d_in[4];
  const float* w_kv  = (const float*)d_in[5];
  const float* w_out = (const float*)d_in[6];
  const float* b_out = (const float*)d_in[7];
  const float* gate  = (const float*)d_in[8];
  float* out = (float*)d_out;
  char* ws = (char*)d_ws;

  unsigned short* XN   = (unsigned short*)(ws);                   // 8 MB  [4096][1024]
  unsigned short* QB   = (unsigned short*)(ws + (8ull  << 20));   // 8 MB  [4096][1024]
  unsigned short* CTXB = (unsigned short*)(ws + (16ull << 20));   // 16 MB [8192][1024]
  unsigned short* KVB  = (unsigned short*)(ws + (32ull << 20));   // 32 MB [8192][2048]
  unsigned short* OB   = (unsigned short*)(ws + (64ull << 20));   // 8 MB  [4096][1024]
  unsigned short* WQT  = (unsigned short*)(ws + (72ull << 20));   // 2 MB  [1024][1024]
  unsigned short* WKVT = (unsigned short*)(ws + (74ull << 20));   // 4 MB  [2048][1024]
  unsigned short* WOT  = (unsigned short*)(ws + (78ull << 20));   // 2 MB  [1024][1024]

  k_prep<<<dim3(12288), dim3(256), 0, stream>>>(w_q, w_kv, w_out, x, gamma, beta, ctx,
                                                WQT, WKVT, WOT, XN, CTXB);
  k_proj<<<dim3(1280), dim3(256), 0, stream>>>(CTXB, XN, WKVT, WQT, KVB, QB);
  k_attn<<<dim3(1024), dim3(256), 0, stream>>>(QB, KVB, OB);
  k_out<<<dim3(512), dim3(256), 0, stream>>>(OB, WOT, out, b_out, gate);
}

// Round 16
// 200.750 us; speedup vs baseline: 1.0161x; 1.0161x over previous
//
#include <hip/hip_runtime.h>
#include <hip/hip_bf16.h>
#include <stdint.h>

#define DIMM  1024
#define NHEAD 16
#define DHEAD 64
#define BB    2
#define SQL   2048
#define SKL   4096
#define KVW   2048   // kv row width = 2*INNER
#define NT    (SKL / 64)

typedef __attribute__((ext_vector_type(8))) short short8;
typedef __attribute__((ext_vector_type(4))) float f32x4;
typedef __attribute__((ext_vector_type(16))) float f32x16;
typedef __attribute__((ext_vector_type(4))) unsigned short us4;

typedef const __attribute__((address_space(1))) uint32_t gu32_t;
typedef __attribute__((address_space(3))) uint32_t lu32_t;

#define GLDS16(gp, lp) __builtin_amdgcn_global_load_lds((gu32_t*)(gp), (lu32_t*)(lp), 16, 0, 0)

static __device__ __forceinline__ unsigned short f2bf(float f) {
  union { float f; uint32_t u; } v; v.f = f;
  uint32_t r = v.u + 0x7fffu + ((v.u >> 16) & 1u);
  return (unsigned short)(r >> 16);
}

// ---------- merged prep: weight transposes + LayerNorm + ctx cast, ONE launch ----------
__global__ __launch_bounds__(256) void k_prep(const float* __restrict__ wq,
                                              const float* __restrict__ wkv,
                                              const float* __restrict__ wot,
                                              const float* __restrict__ x,
                                              const float* __restrict__ gamma,
                                              const float* __restrict__ beta,
                                              const float* __restrict__ ctx,
                                              unsigned short* __restrict__ WQT,
                                              unsigned short* __restrict__ WKVT,
                                              unsigned short* __restrict__ WOT,
                                              unsigned short* __restrict__ XN,
                                              unsigned short* __restrict__ CTXB) {
  const int bid = blockIdx.x;
  const int tid = threadIdx.x;

  if (bid < 4096) {
    __shared__ float tile[32][33];
    const float* in; unsigned short* out; int N, bx, by;
    if (bid < 1024)      {                    in = wq;  out = WQT;  N = 1024; bx = bid & 31; by = bid >> 5; }
    else if (bid < 3072) { int l = bid - 1024; in = wkv; out = WKVT; N = 2048; bx = l & 63; by = l >> 6; }
    else                 { int l = bid - 3072; in = wot; out = WOT;  N = 1024; bx = l & 31; by = l >> 5; }
    const int K = 1024;
    const int n0 = bx * 32, k0 = by * 32;
    const int tx = tid & 31, ty = tid >> 5;
    #pragma unroll
    for (int i = 0; i < 4; i++)
      tile[ty + i * 8][tx] = in[(size_t)(k0 + ty + i * 8) * N + n0 + tx];
    __syncthreads();
    #pragma unroll
    for (int i = 0; i < 4; i++)
      out[(size_t)(n0 + ty + i * 8) * K + k0 + tx] = f2bf(tile[tx][ty + i * 8]);
  } else if (bid < 8192) {
    const int row = bid - 4096;
    const float* xr = x + (size_t)row * DIMM;
    float4 v = *(const float4*)(xr + tid * 4);
    float s = v.x + v.y + v.z + v.w;
    float ss = v.x * v.x + v.y * v.y + v.z * v.z + v.w * v.w;
    #pragma unroll
    for (int m = 1; m < 64; m <<= 1) {
      s += __shfl_xor(s, m);
      ss += __shfl_xor(ss, m);
    }
    __shared__ float red[8];
    const int wid = tid >> 6, lane = tid & 63;
    if (lane == 0) { red[wid] = s; red[4 + wid] = ss; }
    __syncthreads();
    s = red[0] + red[1] + red[2] + red[3];
    ss = red[4] + red[5] + red[6] + red[7];
    float mu = s * (1.0f / DIMM);
    float var = ss * (1.0f / DIMM) - mu * mu;
    float rstd = rsqrtf(var + 1e-5f);
    float4 g = *(const float4*)(gamma + tid * 4);
    float4 bt = *(const float4*)(beta + tid * 4);
    us4 o;
    o.x = f2bf((v.x - mu) * rstd * g.x + bt.x);
    o.y = f2bf((v.y - mu) * rstd * g.y + bt.y);
    o.z = f2bf((v.z - mu) * rstd * g.z + bt.z);
    o.w = f2bf((v.w - mu) * rstd * g.w + bt.w);
    *(us4*)(XN + (size_t)row * DIMM + tid * 4) = o;
  } else {
    size_t i = ((size_t)(bid - 8192) * 256 + tid) * 8;
    float4 v0 = *(const float4*)(ctx + i);
    float4 v1 = *(const float4*)(ctx + i + 4);
    union { us4 h[2]; short8 s; } o;
    o.h[0].x = f2bf(v0.x); o.h[0].y = f2bf(v0.y); o.h[0].z = f2bf(v0.z); o.h[0].w = f2bf(v0.w);
    o.h[1].x = f2bf(v1.x); o.h[1].y = f2bf(v1.y); o.h[1].z = f2bf(v1.z); o.h[1].w = f2bf(v1.w);
    *(short8*)(CTXB + i) = o.s;
  }
}

// ---------- fused projection GEMM: Q = XN@WQT^T and KV = CTXB@WKVT^T ----------
__global__ __launch_bounds__(256) void k_proj(const unsigned short* __restrict__ CTXB,
                                              const unsigned short* __restrict__ XN,
                                              const unsigned short* __restrict__ WKVT,
                                              const unsigned short* __restrict__ WQT,
                                              unsigned short* __restrict__ KVB,
                                              unsigned short* __restrict__ QB) {
  __shared__ unsigned short lA[2][128 * 32];
  __shared__ unsigned short lB[2][128 * 32];
  const int tid = threadIdx.x;
  const int wid = tid >> 6, lane = tid & 63;
  const int kg = lane >> 4, lr = lane & 15;
  const int wr = wid >> 1, wc = wid & 1;
  const int K = 1024, nt = 32;

  const int bid = blockIdx.x;
  const int xcd = bid & 7;
  const int idx = bid >> 3;
  const bool isQ = (idx >= 128);
  int im, in_, N;
  const unsigned short* Ap;
  const unsigned short* Bw;
  unsigned short* Cout;
  if (isQ) { int q = idx - 128; im = xcd * 4 + (q & 3);   in_ = q >> 2;   Bw = WQT;  Cout = QB;  N = 1024; Ap = XN; }
  else     {                    im = xcd * 8 + (idx & 7); in_ = idx >> 3; Bw = WKVT; Cout = KVB; N = 2048; Ap = CTXB; }
  const size_t baseB = (size_t)in_ * 128 * K;
  const unsigned short* Abf = Ap + (size_t)im * 128 * K;

  int ed[2], grow[2], gcol[2];
  #pragma unroll
  for (int j = 0; j < 2; j++) {
    int e = wid * 1024 + j * 512 + lane * 8;
    ed[j] = e;
    int row = e >> 5;
    grow[j] = row;
    gcol[j] = (((e >> 3) & 3) ^ ((row >> 1) & 3)) << 3;
  }

  f32x4 acc[4][4];
  #pragma unroll
  for (int m = 0; m < 4; m++)
    #pragma unroll
    for (int n = 0; n < 4; n++) {
      f32x4 z = {0.0f, 0.0f, 0.0f, 0.0f};
      acc[m][n] = z;
    }

  auto STAGE = [&](int bufi, int t) {
    int k0 = t << 5;
    #pragma unroll
    for (int j = 0; j < 2; j++) {
      GLDS16(Abf + (size_t)grow[j] * K + k0 + gcol[j], &lA[bufi][ed[j]]);
      GLDS16(Bw + baseB + (size_t)grow[j] * K + k0 + gcol[j], &lB[bufi][ed[j]]);
    }
  };
  auto COMPUTE = [&](int bufi) {
    short8 a[4], b[4];
    #pragma unroll
    for (int m = 0; m < 4; m++) {
      int row = wr * 64 + m * 16 + lr;
      a[m] = *(const short8*)&lA[bufi][row * 32 + ((kg ^ ((row >> 1) & 3)) << 3)];
    }
    #pragma unroll
    for (int n = 0; n < 4; n++) {
      int row = wc * 64 + n * 16 + lr;
      b[n] = *(const short8*)&lB[bufi][row * 32 + ((kg ^ ((row >> 1) & 3)) << 3)];
    }
    #pragma unroll
    for (int m = 0; m < 4; m++)
      #pragma unroll
      for (int n = 0; n < 4; n++)
        acc[m][n] = __builtin_amdgcn_mfma_f32_16x16x32_bf16(a[m], b[n], acc[m][n], 0, 0, 0);
  };

  STAGE(0, 0);
  __syncthreads();
  int buf = 0;
  for (int t = 0; t < nt; t++) {
    if (t + 1 < nt) STAGE(buf ^ 1, t + 1);
    COMPUTE(buf);
    __syncthreads();
    buf ^= 1;
  }

  const int r0 = im * 128 + wr * 64;
  const int c0 = in_ * 128 + wc * 64;
  #pragma unroll
  for (int m = 0; m < 4; m++)
    #pragma unroll
    for (int n = 0; n < 4; n++)
      #pragma unroll
      for (int j = 0; j < 4; j++)
        Cout[(size_t)(r0 + m * 16 + kg * 4 + j) * N + c0 + n * 16 + lr] = f2bf(acc[m][n][j]);
}

// ---------- output GEMM: out = (OB@WOT^T + bias) * tanh(gate), f32 out ----------
__global__ __launch_bounds__(256) void k_out(const unsigned short* __restrict__ A,
                                             const unsigned short* __restrict__ BT,
                                             float* __restrict__ C,
                                             const float* __restrict__ bias,
                                             const float* __restrict__ gate) {
  __shared__ unsigned short lA[2][64 * 32];
  __shared__ unsigned short lB[2][128 * 32];
  const int tid = threadIdx.x;
  const int wid = tid >> 6, lane = tid & 63;
  const int kg = lane >> 4, lr = lane & 15;
  const int wr = wid >> 1, wc = wid & 1;
  const int K = 1024, nt = 32, N = 1024;

  const int bid = blockIdx.x;
  const int xcd = bid & 7;
  const int idx = bid >> 3;
  const int im = xcd * 8 + (idx & 7);
  const int in_ = idx >> 3;
  const size_t baseA = (size_t)im * 64 * K;
  const size_t baseB = (size_t)in_ * 128 * K;

  int eA, arow, acol;
  {
    int e = tid * 8;
    eA = e;
    int row = e >> 5;
    arow = row; acol = (((e >> 3) & 3) ^ ((row >> 1) & 3)) << 3;
  }
  int eB[2], brow[2], bcol[2];
  #pragma unroll
  for (int j = 0; j < 2; j++) {
    int e = tid * 8 + j * 2048;
    eB[j] = e;
    int row = e >> 5;
    brow[j] = row; bcol[j] = (((e >> 3) & 3) ^ ((row >> 1) & 3)) << 3;
  }

  f32x4 acc[2][4];
  #pragma unroll
  for (int m = 0; m < 2; m++)
    #pragma unroll
    for (int n = 0; n < 4; n++) {
      f32x4 z = {0.0f, 0.0f, 0.0f, 0.0f};
      acc[m][n] = z;
    }

  auto STAGE = [&](int bufi, int t) {
    int k0 = t << 5;
    GLDS16(A + baseA + (size_t)arow * K + k0 + acol, &lA[bufi][eA]);
    #pragma unroll
    for (int j = 0; j < 2; j++)
      GLDS16(BT + baseB + (size_t)brow[j] * K + k0 + bcol[j], &lB[bufi][eB[j]]);
  };

  STAGE(0, 0);
  __syncthreads();
  int buf = 0;
  for (int t = 0; t < nt; t++) {
    if (t + 1 < nt) STAGE(buf ^ 1, t + 1);
    short8 a[2], b[4];
    #pragma unroll
    for (int m = 0; m < 2; m++) {
      int row = wr * 32 + m * 16 + lr;
      a[m] = *(const short8*)&lA[buf][row * 32 + ((kg ^ ((row >> 1) & 3)) << 3)];
    }
    #pragma unroll
    for (int n = 0; n < 4; n++) {
      int row = wc * 64 + n * 16 + lr;
      b[n] = *(const short8*)&lB[buf][row * 32 + ((kg ^ ((row >> 1) & 3)) << 3)];
    }
    #pragma unroll
    for (int m = 0; m < 2; m++)
      #pragma unroll
      for (int n = 0; n < 4; n++)
        acc[m][n] = __builtin_amdgcn_mfma_f32_16x16x32_bf16(a[m], b[n], acc[m][n], 0, 0, 0);
    __syncthreads();
    buf ^= 1;
  }

  const int r0 = im * 64 + wr * 32;
  const int c0 = in_ * 128 + wc * 64;
  float gl = tanhf(gate[0]);
  #pragma unroll
  for (int m = 0; m < 2; m++)
    #pragma unroll
    for (int n = 0; n < 4; n++)
      #pragma unroll
      for (int j = 0; j < 4; j++) {
        int col = c0 + n * 16 + lr;
        C[(size_t)(r0 + m * 16 + kg * 4 + j) * N + col] = (acc[m][n][j] + bias[col]) * gl;
      }
}

// ---------- flash attention (v9, best measured 98 us — FROZEN) ----------
__global__ __launch_bounds__(256, 4) void k_attn(const unsigned short* __restrict__ Q,
                                                 const unsigned short* __restrict__ KV,
                                                 unsigned short* __restrict__ O) {
  __shared__ unsigned short sK[2][64 * 64];   // [key][d], granule-swizzled via source
  __shared__ unsigned short sV[2][64 * 64];   // subtiled [key/4][d/16][4][16]

  const int tid = threadIdx.x;
  const int wave = tid >> 6, lane = tid & 63;
  const int wq = wave & 1, wk = wave >> 1;
  const int l31 = lane & 31, hi = lane >> 5;

  const int wid_b = blockIdx.x;
  const int work = (wid_b & 7) * 128 + (wid_b >> 3);
  const int qb = work & 31, bh = work >> 5;
  const int b = bh >> 4, h = bh & 15;

  const unsigned short* Qp = Q + (size_t)b * SQL * DIMM + h * DHEAD;
  const unsigned short* Kp = KV + (size_t)b * SKL * KVW + h * DHEAD;
  const unsigned short* Vp = Kp + DIMM;

  const int qr0 = qb * 64 + wq * 32;

  const unsigned short* ksrc[2]; int kdst[2];
  const unsigned short* vsrc[2]; int vdst[2];
  #pragma unroll
  for (int j = 0; j < 2; j++) {
    int e = (tid + j * 256) * 8;
    int row = e >> 6;
    int col = (((e >> 3) & 7) ^ (row & 7)) << 3;
    ksrc[j] = Kp + (size_t)row * KVW + col;
    kdst[j] = e;
    int g = tid + j * 256;
    int key = (g >> 5) * 4 + ((g >> 1) & 3);
    int d0v = ((g >> 3) & 3) * 16 + (g & 1) * 8;
    vsrc[j] = Vp + (size_t)key * KVW + d0v;
    vdst[j] = g * 8;
  }

  auto STAGE = [&](int bufi, int kt) {
    size_t off = (size_t)kt * 64 * KVW;
    #pragma unroll
    for (int j = 0; j < 2; j++) GLDS16(ksrc[j] + off, &sK[bufi][kdst[j]]);
    #pragma unroll
    for (int j = 0; j < 2; j++) GLDS16(vsrc[j] + off, &sV[bufi][vdst[j]]);
  };

  short8 qa[4];
  #pragma unroll
  for (int t = 0; t < 4; t++) {
    short8 v = *(const short8*)(Qp + (size_t)(qr0 + l31) * DIMM + t * 16 + hi * 8);
    #pragma unroll
    for (int j = 0; j < 8; j++) {
      union { float f; uint32_t u; } c;
      c.u = ((uint32_t)(unsigned short)v[j]) << 16;
      v[j] = (short)f2bf(c.f * 0.1803368801111f);  // 0.125 * log2(e)
    }
    qa[t] = v;
  }

  f32x16 oacc[2];
  #pragma unroll
  for (int d2 = 0; d2 < 2; d2++)
    #pragma unroll
    for (int r = 0; r < 16; r++) oacc[d2][r] = 0.0f;
  float rs = 0.0f;

  const uint32_t sVb0 = (uint32_t)(size_t)(lu32_t*)&sV[0][0] +
                        (uint32_t)(hi * 1024 + ((lane >> 4) & 1) * 128 + (lane & 15) * 8);

  STAGE(0, 0);
  __syncthreads();

  union u4s8 { uint32_t u[4]; short8 s; };

  int buf = 0;
  for (int kt = 0; kt < NT; kt++) {
    if (kt + 1 < NT) STAGE(buf ^ 1, kt + 1);

    short8 kbf[4];
    {
      int row = wk * 32 + l31;
      #pragma unroll
      for (int t = 0; t < 4; t++) {
        int gl = t * 2 + hi;
        kbf[t] = *(const short8*)&sK[buf][row * 64 + ((gl ^ (row & 7)) << 3)];
      }
    }

    f32x16 sc;
    #pragma unroll
    for (int r = 0; r < 16; r++) sc[r] = 0.0f;
    #pragma unroll
    for (int t = 0; t < 4; t++)
      sc = __builtin_amdgcn_mfma_f32_32x32x16_bf16(kbf[t], qa[t], sc, 0, 0, 0);

    float p[16];
    #pragma unroll
    for (int r = 0; r < 16; r++) {
      p[r] = __builtin_amdgcn_exp2f(sc[r]);
      rs += p[r];
    }
    uint32_t w[8];
    #pragma unroll
    for (int i = 0; i < 8; i++)
      asm("v_cvt_pk_bf16_f32 %0, %1, %2" : "=v"(w[i]) : "v"(p[2 * i]), "v"(p[2 * i + 1]));
    asm("v_permlane32_swap_b32 %0, %1" : "+v"(w[0]), "+v"(w[2]));
    asm("v_permlane32_swap_b32 %0, %1" : "+v"(w[1]), "+v"(w[3]));
    asm("v_permlane32_swap_b32 %0, %1" : "+v"(w[4]), "+v"(w[6]));
    asm("v_permlane32_swap_b32 %0, %1" : "+v"(w[5]), "+v"(w[7]));
    u4s8 paf[2];
    paf[0].u[0] = w[0]; paf[0].u[1] = w[1]; paf[0].u[2] = w[2]; paf[0].u[3] = w[3];
    paf[1].u[0] = w[4]; paf[1].u[1] = w[5]; paf[1].u[2] = w[6]; paf[1].u[3] = w[7];

    u4s8 vb[2][2];
    {
      uint32_t tb = sVb0 + (uint32_t)(buf * 8192 + wk * 4096);
      #pragma unroll
      for (int d2 = 0; d2 < 2; d2++)
        #pragma unroll
        for (int ks = 0; ks < 2; ks++) {
          uint2 t0, t1;
          uint32_t a0 = tb + (uint32_t)(ks * 2048 + d2 * 256);
          asm volatile("ds_read_b64_tr_b16 %0, %1" : "=v"(t0) : "v"(a0));
          asm volatile("ds_read_b64_tr_b16 %0, %1" : "=v"(t1) : "v"(a0 + 512u));
          vb[d2][ks].u[0] = t0.x; vb[d2][ks].u[1] = t0.y;
          vb[d2][ks].u[2] = t1.x; vb[d2][ks].u[3] = t1.y;
        }
    }
    asm volatile("s_waitcnt lgkmcnt(0)" ::: "memory");
    __builtin_amdgcn_sched_barrier(0);

    #pragma unroll
    for (int d2 = 0; d2 < 2; d2++)
      #pragma unroll
      for (int ks = 0; ks < 2; ks++)
        oacc[d2] = __builtin_amdgcn_mfma_f32_32x32x16_bf16(paf[ks].s, vb[d2][ks].s, oacc[d2], 0, 0, 0);

    __syncthreads();
    buf ^= 1;
  }

  float* sRed = (float*)&sK[0][0];
  float* sRs  = (float*)&sV[0][0];
  if (wk == 1) {
    #pragma unroll
    for (int d2 = 0; d2 < 2; d2++)
      #pragma unroll
      for (int r = 0; r < 16; r++)
        sRed[((wq * 2 + d2) * 16 + r) * 64 + lane] = oacc[d2][r];
    sRs[wq * 64 + lane] = rs;
  }
  __syncthreads();
  if (wk == 0) {
    #pragma unroll
    for (int d2 = 0; d2 < 2; d2++)
      #pragma unroll
      for (int r = 0; r < 16; r++)
        oacc[d2][r] += sRed[((wq * 2 + d2) * 16 + r) * 64 + lane];
    float rs2 = rs + sRs[wq * 64 + lane];
    float t = rs2 + __shfl_xor(rs2, 32);
    float inv = 1.0f / t;
    float rq[16];
    #pragma unroll
    for (int r = 0; r < 16; r++) {
      int rho = (r & 3) + 8 * (r >> 2) + 4 * hi;
      rq[r] = __shfl(inv, rho);
    }
    unsigned short* Op = O + (size_t)b * SQL * DIMM + h * DHEAD;
    #pragma unroll
    for (int d2 = 0; d2 < 2; d2++)
      #pragma unroll
      for (int r = 0; r < 16; r++) {
        int rho = (r & 3) + 8 * (r >> 2) + 4 * hi;
        Op[(size_t)(qr0 + rho) * DIMM + d2 * 32 + l31] = f2bf(oacc[d2][r] * rq[r]);
      }
  }
}

extern "C" void kernel_launch(void* const* d_in, const int* in_sizes, int n_in,
                              void* d_out, int out_size, void* d_ws, size_t ws_size,
                              hipStream_t stream) {
  (void)in_sizes; (void)n_in; (void)out_size; (void)ws_size;
  const float* x     = (const float*)d_in[0];
  const float* ctx   = (const float*)d_in[1];
  const float* gamma = (const float*)d_in[2];
  const float* beta  = (const float*)d_in[3];
  const float* w_q   = (const float*)d_in[4];
  const float* w_kv  = (const float*)d_in[5];
  const float* w_out = (const float*)d_in[6];
  const float* b_out = (const float*)d_in[7];
  const float* gate  = (const float*)d_in[8];
  float* out = (float*)d_out;
  char* ws = (char*)d_ws;

  unsigned short* XN   = (unsigned short*)(ws);                   // 8 MB  [4096][1024]
  unsigned short* QB   = (unsigned short*)(ws + (8ull  << 20));   // 8 MB  [4096][1024]
  unsigned short* CTXB = (unsigned short*)(ws + (16ull << 20));   // 16 MB [8192][1024]
  unsigned short* KVB  = (unsigned short*)(ws + (32ull << 20));   // 32 MB [8192][2048]
  unsigned short* OB   = (unsigned short*)(ws + (64ull << 20));   // 8 MB  [4096][1024]
  unsigned short* WQT  = (unsigned short*)(ws + (72ull << 20));   // 2 MB  [1024][1024]
  unsigned short* WKVT = (unsigned short*)(ws + (74ull << 20));   // 4 MB  [2048][1024]
  unsigned short* WOT  = (unsigned short*)(ws + (78ull << 20));   // 2 MB  [1024][1024]

  k_prep<<<dim3(12288), dim3(256), 0, stream>>>(w_q, w_kv, w_out, x, gamma, beta, ctx,
                                                WQT, WKVT, WOT, XN, CTXB);
  k_proj<<<dim3(1280), dim3(256), 0, stream>>>(CTXB, XN, WKVT, WQT, KVB, QB);
  k_attn<<<dim3(1024), dim3(256), 0, stream>>>(QB, KVB, OB);
  k_out<<<dim3(512), dim3(256), 0, stream>>>(OB, WOT, out, b_out, gate);
}